// Round 12
// baseline (216.843 us; speedup 1.0000x reference)
//
#include <hip/hip_runtime.h>

#define NRELS 8

typedef __attribute__((ext_vector_type(8))) short short8;
typedef __attribute__((ext_vector_type(4))) float f32x4;

__device__ __forceinline__ unsigned short f2bf(float f) {
  unsigned int u = __float_as_uint(f);
  u += 0x7FFFu + ((u >> 16) & 1u);
  return (unsigned short)(u >> 16);
}
__device__ __forceinline__ float bf2f(unsigned short h) {
  return __uint_as_float(((unsigned int)h) << 16);
}

__device__ __forceinline__ void gload_lds16(const void* g, void* l) {
  __builtin_amdgcn_global_load_lds(
      (const __attribute__((address_space(1))) unsigned int*)g,
      (__attribute__((address_space(3))) unsigned int*)l, 16, 0, 0);
}

// ---------------- zero scratch ----------------

__global__ __launch_bounds__(256) void zero_kernel(int* __restrict__ p, int n) {
  int i = blockIdx.x * blockDim.x + threadIdx.x;
  if (i < n) p[i] = 0;
}

// ---------------- histogram over (dst,rel) keys ----------------

__global__ __launch_bounds__(256) void hist_kernel(
    const int* __restrict__ dstp, const int* __restrict__ et, int E,
    int* __restrict__ hist) {
  int i = blockIdx.x * blockDim.x + threadIdx.x;
  if (i < E) {
    atomicAdd(&hist[(size_t)dstp[i] * NRELS + et[i]], 1);
  }
}

// ---------------- hierarchical exclusive scan over M = 8N keys + norm table -------

__global__ __launch_bounds__(256) void scan1_kernel(
    const int* __restrict__ hist, int M, int* __restrict__ row_off,
    int* __restrict__ bsum, float* __restrict__ nrm) {
  __shared__ int s[256];
  int t = threadIdx.x;
  int i = blockIdx.x * 256 + t;
  int v = (i < M) ? hist[i] : 0;
  if (i < M) nrm[i] = 1.0f / (float)max(v, 1);
  s[t] = v;
  __syncthreads();
  for (int off = 1; off < 256; off <<= 1) {
    int u = (t >= off) ? s[t - off] : 0;
    __syncthreads();
    s[t] += u;
    __syncthreads();
  }
  if (i < M) row_off[i] = s[t] - v;  // local exclusive
  if (t == 255) bsum[blockIdx.x] = s[255];
}

__global__ __launch_bounds__(256) void scan2_kernel(int* __restrict__ bsum, int NB) {
  __shared__ int s[256];
  int t = threadIdx.x;
  int C = (NB + 255) / 256;
  int b0 = t * C, b1 = min(NB, b0 + C);
  int sum = 0;
  for (int i = b0; i < b1; i++) sum += bsum[i];
  s[t] = sum;
  __syncthreads();
  for (int off = 1; off < 256; off <<= 1) {
    int u = (t >= off) ? s[t - off] : 0;
    __syncthreads();
    s[t] += u;
    __syncthreads();
  }
  int base = (t == 0) ? 0 : s[t - 1];
  for (int i = b0; i < b1; i++) {
    int v = bsum[i];
    bsum[i] = base;
    base += v;
  }
  if (t == 255) bsum[NB] = s[255];
}

__global__ __launch_bounds__(256) void scan3_kernel(
    int* __restrict__ row_off, int* __restrict__ cursor,
    const int* __restrict__ bsum, int M, int NB) {
  int i = blockIdx.x * 256 + threadIdx.x;
  if (i < M) {
    int v = row_off[i] + bsum[i >> 8];
    row_off[i] = v;
    cursor[i] = v;
  } else if (i == M) {
    row_off[M] = bsum[NB];
  }
}

// ---------------- bucket edges by (dst,rel); store src | rel<<20 ----------------

__global__ __launch_bounds__(256) void bucket_kernel(
    const int* __restrict__ src, const int* __restrict__ dstp,
    const int* __restrict__ et, int E, int* __restrict__ cursor,
    int* __restrict__ epack) {
  int i = blockIdx.x * blockDim.x + threadIdx.x;
  if (i < E) {
    int r = et[i];
    int pos = atomicAdd(&cursor[(size_t)dstp[i] * NRELS + r], 1);
    epack[pos] = src[i] | (r << 20);
  }
}

// ---------------- fp32 -> bf16 feature conversion ----------------

__global__ __launch_bounds__(256) void cvt_x_kernel(
    const float* __restrict__ x, unsigned short* __restrict__ xb, int n4) {
  int i = blockIdx.x * blockDim.x + threadIdx.x;
  if (i < n4) {
    float4 v = ((const float4*)x)[i];
    ushort4 o;
    o.x = f2bf(v.x); o.y = f2bf(v.y); o.z = f2bf(v.z); o.w = f2bf(v.w);
    ((ushort4*)xb)[i] = o;
  }
}

// ---- weights -> bf16, transposed to Bt[n][k] (k contiguous, 128 wide) ----

__global__ __launch_bounds__(256) void cvt_w_kernel(
    const float* __restrict__ W1, const float* __restrict__ root1,
    const float* __restrict__ W2, const float* __restrict__ root2,
    unsigned short* __restrict__ Bt1, unsigned short* __restrict__ Bt2) {
  int idx = blockIdx.x * blockDim.x + threadIdx.x;
  const int T1 = 1152 * 128;
  const int T2 = 576 * 128;
  if (idx < T1) {
    int n = idx >> 7, k = idx & 127;
    float v;
    if (n < 1024) {
      int r = n >> 7, c = n & 127;
      v = W1[((size_t)r * 128 + k) * 128 + c];
    } else {
      v = root1[(size_t)k * 128 + (n - 1024)];
    }
    Bt1[idx] = f2bf(v);
  } else if (idx < T1 + T2) {
    int j = idx - T1;
    int n = j >> 7, k = j & 127;
    float v;
    if (n < 512) {
      int r = n >> 6, c = n & 63;
      v = W2[((size_t)r * 128 + k) * 64 + c];
    } else {
      v = root2[(size_t)k * 64 + (n - 512)];
    }
    Bt2[j] = f2bf(v);
  }
}

// ---------------- MFMA GEMM: xs[N,NC] = A[N,128] @ Bt[NC,128]^T (bf16 out) --------
// BN=64 col-tiles, TILES per block. A staged once; B double-buffered with counted
// vmcnt so next tile's loads fly under current MFMA; epilogue staged through the
// consumed B buffer for fully-coalesced 16B/lane stores.

template <int TILES>
__global__ __launch_bounds__(256) void gemm_xs(
    const unsigned short* __restrict__ A,   // [N][128] bf16
    const unsigned short* __restrict__ Bt,  // [NC][128] bf16
    unsigned short* __restrict__ Cout,      // [N][NC] bf16
    int N, int NC) {
  constexpr int BN = 64;

  __shared__ unsigned short As[64 * 128];      // 16 KB, 256B rows
  __shared__ unsigned short Bs[2][64 * 128];   // 2 x 16 KB

  const int tid = threadIdx.x;
  const int lane = tid & 63;
  const int wid = tid >> 6;
  const int wm = wid >> 1, wn = wid & 1;
  const int l15 = lane & 15, lhi = lane >> 4;
  const int bm0 = blockIdx.y * 64;
  const int ng0 = blockIdx.x * BN * TILES;

  // stage A: 64 rows x 256 B (full K) — once. 4 loads/thread.
#pragma unroll
  for (int c = 0; c < 4; c++) {
    int o = c * 4096 + tid * 16;
    int row = o >> 8;
    int scol = ((o & 255) ^ ((row & 7) << 4)) >> 1;
    int gr = bm0 + row;
    gr = gr < N ? gr : N - 1;
    gload_lds16(A + (size_t)gr * 128 + scol, (char*)As + o);
  }
  // stage B tile 0. 4 loads/thread.
#pragma unroll
  for (int c = 0; c < 4; c++) {
    int o = c * 4096 + tid * 16;
    int n = o >> 8;
    int scol = ((o & 255) ^ ((n & 7) << 4)) >> 1;
    gload_lds16(Bt + (size_t)(ng0 + n) * 128 + scol, (char*)Bs[0] + o);
  }

  for (int t = 0; t < TILES; t++) {
    const int bb = t & 1;
    const int n0 = ng0 + t * BN;
    __syncthreads();  // Bs[bb^1] free (t-1 compute + C-readout done)
    if (t + 1 < TILES) {
      const int n1 = n0 + BN;
#pragma unroll
      for (int c = 0; c < 4; c++) {
        int o = c * 4096 + tid * 16;
        int n = o >> 8;
        int scol = ((o & 255) ^ ((n & 7) << 4)) >> 1;
        gload_lds16(Bt + (size_t)(n1 + n) * 128 + scol, (char*)Bs[bb ^ 1] + o);
      }
      asm volatile("s_waitcnt vmcnt(4)" ::: "memory");  // wait B_t (next 4 in flight)
    } else {
      asm volatile("s_waitcnt vmcnt(0)" ::: "memory");
    }
    __syncthreads();  // all threads' B_t staged

    f32x4 acc[2][2];
#pragma unroll
    for (int i = 0; i < 2; i++)
#pragma unroll
      for (int j = 0; j < 2; j++) acc[i][j] = (f32x4){0.f, 0.f, 0.f, 0.f};

#pragma unroll
    for (int ks = 0; ks < 4; ks++) {
      short8 af[2], bf[2];
#pragma unroll
      for (int fm = 0; fm < 2; fm++) {
        int row = wm * 32 + fm * 16 + l15;
        af[fm] = *(const short8*)((const char*)As + row * 256 +
                                  ((ks * 64 + lhi * 16) ^ ((row & 7) << 4)));
      }
#pragma unroll
      for (int fn = 0; fn < 2; fn++) {
        int n = wn * 32 + fn * 16 + l15;
        bf[fn] = *(const short8*)((const char*)Bs[bb] + n * 256 +
                                  ((ks * 64 + lhi * 16) ^ ((n & 7) << 4)));
      }
#pragma unroll
      for (int fm = 0; fm < 2; fm++)
#pragma unroll
        for (int fn = 0; fn < 2; fn++)
          acc[fm][fn] = __builtin_amdgcn_mfma_f32_16x16x32_bf16(
              af[fm], bf[fn], acc[fm][fn], 0, 0, 0);
    }

    __syncthreads();  // all reads of Bs[bb] done -> reuse as C-stage

    // acc -> bf16 C-tile in Bs[bb]: [64 rows][64 cols], 128B rows, XOR16 swizzle
#pragma unroll
    for (int fm = 0; fm < 2; fm++) {
#pragma unroll
      for (int fn = 0; fn < 2; fn++) {
        int col = wn * 32 + fn * 16 + l15;
#pragma unroll
        for (int i = 0; i < 4; i++) {
          int row = wm * 32 + fm * 16 + lhi * 4 + i;
          int byte = (row * 128 + col * 2) ^ ((row & 7) << 4);
          *(unsigned short*)((char*)Bs[bb] + byte) = f2bf(acc[fm][fn][i]);
        }
      }
    }
    __syncthreads();

    // coalesced readout: 2 x 16B per thread; wave = 1024B = 8 rows' 128B chunks
#pragma unroll
    for (int j = 0; j < 2; j++) {
      int flat = j * 4096 + tid * 16;
      int row = flat >> 7;
      int k16 = flat & 127;
      int grow = bm0 + row;
      if (grow < N) {
        short8 v = *(const short8*)((const char*)Bs[bb] + row * 128 +
                                    (k16 ^ ((row & 7) << 4)));
        *(short8*)((char*)(Cout + (size_t)grow * NC + n0) + k16) = v;
      }
    }
  }
}

// ---------------- agg-finish layer 1: flat per-edge loop, 8-deep MLP ----------

__global__ __launch_bounds__(256) void agg_finish1(
    const unsigned short* __restrict__ xs,  // [N][1152] bf16
    const int* __restrict__ row_off,        // [8N+1]
    const int* __restrict__ epack,          // [E] src | rel<<20
    const float* __restrict__ nrm,          // [8N]
    const float* __restrict__ b1,           // [128]
    unsigned short* __restrict__ h,         // [N][128] bf16 out (relu'd)
    int N) {
  int wid = (int)((blockIdx.x * blockDim.x + threadIdx.x) >> 6);
  if (wid >= N) return;
  int lane = threadIdx.x & 63;
  int lo2 = lane * 2;
  unsigned int own = *(const unsigned int*)(xs + (size_t)wid * 1152 + 1024 + lo2);
  float acc0 = bf2f((unsigned short)(own & 0xFFFF)) + b1[lo2];
  float acc1 = bf2f((unsigned short)(own >> 16)) + b1[lo2 + 1];
  int kb = wid * NRELS;
  int b = row_off[kb], e = row_off[kb + NRELS];
  int i = b;
  for (; i + 7 < e; i += 8) {
    unsigned int u[8];
    float nv[8];
#pragma unroll
    for (int q = 0; q < 8; q++) {
      int p = epack[i + q];
      u[q] = *(const unsigned int*)(xs + (size_t)(p & 0xFFFFF) * 1152 + ((p >> 20) << 7) + lo2);
      nv[q] = nrm[kb + (p >> 20)];
    }
#pragma unroll
    for (int q = 0; q < 8; q++) {
      acc0 += bf2f((unsigned short)(u[q] & 0xFFFF)) * nv[q];
      acc1 += bf2f((unsigned short)(u[q] >> 16)) * nv[q];
    }
  }
  for (; i < e; i++) {
    int p = epack[i];
    unsigned int u = *(const unsigned int*)(xs + (size_t)(p & 0xFFFFF) * 1152 + ((p >> 20) << 7) + lo2);
    float nv = nrm[kb + (p >> 20)];
    acc0 += bf2f((unsigned short)(u & 0xFFFF)) * nv;
    acc1 += bf2f((unsigned short)(u >> 16)) * nv;
  }
  unsigned int o = (unsigned int)f2bf(fmaxf(acc0, 0.f)) |
                   ((unsigned int)f2bf(fmaxf(acc1, 0.f)) << 16);
  *(unsigned int*)(h + (size_t)wid * 128 + lo2) = o;
}

// ---------------- agg-finish layer 2: flat per-edge loop (64 cols, fp32 out) ------

__global__ __launch_bounds__(256) void agg_finish2(
    const unsigned short* __restrict__ ys,  // [N][576] bf16
    const int* __restrict__ row_off,        // [8N+1]
    const int* __restrict__ epack,          // [E] src | rel<<20
    const float* __restrict__ nrm,          // [8N]
    const float* __restrict__ b2,           // [64]
    float* __restrict__ outp,               // [N][64] fp32
    int N) {
  int wid = (int)((blockIdx.x * blockDim.x + threadIdx.x) >> 6);
  if (wid >= N) return;
  int col = threadIdx.x & 63;
  float acc = bf2f(ys[(size_t)wid * 576 + 512 + col]) + b2[col];
  int kb = wid * NRELS;
  int b = row_off[kb], e = row_off[kb + NRELS];
  int i = b;
  for (; i + 7 < e; i += 8) {
    float v[8], nv[8];
#pragma unroll
    for (int q = 0; q < 8; q++) {
      int p = epack[i + q];
      v[q] = bf2f(ys[(size_t)(p & 0xFFFFF) * 576 + ((p >> 20) << 6) + col]);
      nv[q] = nrm[kb + (p >> 20)];
    }
#pragma unroll
    for (int q = 0; q < 8; q++) acc += v[q] * nv[q];
  }
  for (; i < e; i++) {
    int p = epack[i];
    acc += bf2f(ys[(size_t)(p & 0xFFFFF) * 576 + ((p >> 20) << 6) + col]) * nrm[kb + (p >> 20)];
  }
  outp[(size_t)wid * 64 + col] = acc;
}

// ---------------- launch ----------------

extern "C" void kernel_launch(void* const* d_in, const int* in_sizes, int n_in,
                              void* d_out, int out_size, void* d_ws, size_t ws_size,
                              hipStream_t stream) {
  const float* x     = (const float*)d_in[0];
  const int*   eidx  = (const int*)d_in[1];
  const int*   et    = (const int*)d_in[2];
  const float* W1    = (const float*)d_in[3];
  const float* root1 = (const float*)d_in[4];
  const float* b1    = (const float*)d_in[5];
  const float* W2    = (const float*)d_in[6];
  const float* root2 = (const float*)d_in[7];
  const float* b2    = (const float*)d_in[8];
  float* out = (float*)d_out;

  const int IN = 128;
  const int N = in_sizes[0] / IN;
  const int E = in_sizes[2];
  const int* src = eidx;
  const int* dst = eidx + E;
  const int M = N * NRELS;            // (dst,rel) key space
  const int NB = (M + 255) / 256;

  auto align = [](size_t v) { return (v + 255) & ~(size_t)255; };
  char* base = (char*)d_ws;
  size_t o = 0;
  int* hist = (int*)(base + o);
  o = align((size_t)M * 4);
  int* row_off = (int*)(base + o);
  o = align(o + (size_t)(M + 1) * 4);
  int* cursor = (int*)(base + o);
  o = align(o + (size_t)M * 4);
  int* bsum = (int*)(base + o);
  o = align(o + (size_t)(NB + 1) * 4);
  float* nrm = (float*)(base + o);
  o = align(o + (size_t)M * 4);
  int* epack = (int*)(base + o);
  o = align(o + (size_t)E * 4);
  unsigned short* xb = (unsigned short*)(base + o);       // [N][128] bf16
  o = align(o + (size_t)N * 128 * 2);
  unsigned short* hb = (unsigned short*)(base + o);       // [N][128] bf16 (relu'd h)
  o = align(o + (size_t)N * 128 * 2);
  unsigned short* Bt1 = (unsigned short*)(base + o);      // [1152][128]
  o = align(o + (size_t)1152 * 128 * 2);
  unsigned short* Bt2 = (unsigned short*)(base + o);      // [576][128]
  o = align(o + (size_t)576 * 128 * 2);
  unsigned short* xs = (unsigned short*)(base + o);       // [N][1152] bf16 (reused as ys)

  const int tb = 256;
  zero_kernel<<<(M + tb - 1) / tb, tb, 0, stream>>>(hist, M);
  hist_kernel<<<(E + tb - 1) / tb, tb, 0, stream>>>(dst, et, E, hist);
  scan1_kernel<<<NB, 256, 0, stream>>>(hist, M, row_off, bsum, nrm);
  scan2_kernel<<<1, 256, 0, stream>>>(bsum, NB);
  scan3_kernel<<<(M + 256) / 256, 256, 0, stream>>>(row_off, cursor, bsum, M, NB);
  bucket_kernel<<<(E + tb - 1) / tb, tb, 0, stream>>>(src, dst, et, E, cursor, epack);
  cvt_x_kernel<<<(N * 128 / 4 + tb - 1) / tb, tb, 0, stream>>>(x, xb, N * 128 / 4);
  cvt_w_kernel<<<((1152 + 576) * 128 + tb - 1) / tb, tb, 0, stream>>>(
      W1, root1, W2, root2, Bt1, Bt2);

  const int agrid = (N + 3) / 4;
  const int gblocks = (N + 63) / 64;

  // layer 1: xs = xb @ Bt1^T ; h = relu(agg(xs) + root-slice + b1)
  {
    dim3 g(3, gblocks);  // 3 col-groups x 6 tiles of 64 = 1152
    gemm_xs<6><<<g, 256, 0, stream>>>(xb, Bt1, xs, N, 1152);
  }
  agg_finish1<<<agrid, 256, 0, stream>>>(xs, row_off, epack, nrm, b1, hb, N);

  // layer 2: ys = hb @ Bt2^T ; out = agg(ys) + root-slice + b2
  {
    dim3 g(3, gblocks);  // 3 col-groups x 3 tiles of 64 = 576
    gemm_xs<3><<<g, 256, 0, stream>>>(hb, Bt2, xs, N, 576);
  }
  agg_finish2<<<agrid, 256, 0, stream>>>(xs, row_off, epack, nrm, b2, out, N);
}

// Round 13
// 204.881 us; speedup vs baseline: 1.0584x; 1.0584x over previous
//
#include <hip/hip_runtime.h>

#define NRELS 8

typedef __attribute__((ext_vector_type(8))) short short8;
typedef __attribute__((ext_vector_type(4))) float f32x4;

__device__ __forceinline__ unsigned short f2bf(float f) {
  unsigned int u = __float_as_uint(f);
  u += 0x7FFFu + ((u >> 16) & 1u);
  return (unsigned short)(u >> 16);
}
__device__ __forceinline__ float bf2f(unsigned short h) {
  return __uint_as_float(((unsigned int)h) << 16);
}

__device__ __forceinline__ void gload_lds16(const void* g, void* l) {
  __builtin_amdgcn_global_load_lds(
      (const __attribute__((address_space(1))) unsigned int*)g,
      (__attribute__((address_space(3))) unsigned int*)l, 16, 0, 0);
}

// ---------------- zero scratch ----------------

__global__ __launch_bounds__(256) void zero_kernel(int* __restrict__ p, int n) {
  int i = blockIdx.x * blockDim.x + threadIdx.x;
  if (i < n) p[i] = 0;
}

// ---------------- fused prep: cvt_x | cvt_w | hist (independent ranges) -----------

__global__ __launch_bounds__(256) void prep_kernel(
    const float* __restrict__ x, unsigned short* __restrict__ xb, int n4,
    const float* __restrict__ W1, const float* __restrict__ root1,
    const float* __restrict__ W2, const float* __restrict__ root2,
    unsigned short* __restrict__ Bt1, unsigned short* __restrict__ Bt2,
    const int* __restrict__ dstp, const int* __restrict__ et, int E,
    int* __restrict__ hist) {
  const int T1 = 1152 * 128;
  const int T2 = 576 * 128;
  int i = blockIdx.x * blockDim.x + threadIdx.x;
  if (i < n4) {
    float4 v = ((const float4*)x)[i];
    ushort4 o;
    o.x = f2bf(v.x); o.y = f2bf(v.y); o.z = f2bf(v.z); o.w = f2bf(v.w);
    ((ushort4*)xb)[i] = o;
    return;
  }
  i -= n4;
  if (i < T1) {
    int n = i >> 7, k = i & 127;
    float v;
    if (n < 1024) {
      int r = n >> 7, c = n & 127;
      v = W1[((size_t)r * 128 + k) * 128 + c];
    } else {
      v = root1[(size_t)k * 128 + (n - 1024)];
    }
    Bt1[i] = f2bf(v);
    return;
  }
  i -= T1;
  if (i < T2) {
    int n = i >> 7, k = i & 127;
    float v;
    if (n < 512) {
      int r = n >> 6, c = n & 63;
      v = W2[((size_t)r * 128 + k) * 64 + c];
    } else {
      v = root2[(size_t)k * 64 + (n - 512)];
    }
    Bt2[i] = f2bf(v);
    return;
  }
  i -= T2;
  if (i < E) {
    atomicAdd(&hist[(size_t)dstp[i] * NRELS + et[i]], 1);
  }
}

// ---------------- hierarchical exclusive scan over M = 8N keys + norm table -------

__global__ __launch_bounds__(256) void scan1_kernel(
    const int* __restrict__ hist, int M, int* __restrict__ row_off,
    int* __restrict__ bsum, float* __restrict__ nrm) {
  __shared__ int s[256];
  int t = threadIdx.x;
  int i = blockIdx.x * 256 + t;
  int v = (i < M) ? hist[i] : 0;
  if (i < M) nrm[i] = 1.0f / (float)max(v, 1);
  s[t] = v;
  __syncthreads();
  for (int off = 1; off < 256; off <<= 1) {
    int u = (t >= off) ? s[t - off] : 0;
    __syncthreads();
    s[t] += u;
    __syncthreads();
  }
  if (i < M) row_off[i] = s[t] - v;  // local exclusive
  if (t == 255) bsum[blockIdx.x] = s[255];
}

__global__ __launch_bounds__(256) void scan2_kernel(int* __restrict__ bsum, int NB) {
  __shared__ int s[256];
  int t = threadIdx.x;
  int C = (NB + 255) / 256;
  int b0 = t * C, b1 = min(NB, b0 + C);
  int sum = 0;
  for (int i = b0; i < b1; i++) sum += bsum[i];
  s[t] = sum;
  __syncthreads();
  for (int off = 1; off < 256; off <<= 1) {
    int u = (t >= off) ? s[t - off] : 0;
    __syncthreads();
    s[t] += u;
    __syncthreads();
  }
  int base = (t == 0) ? 0 : s[t - 1];
  for (int i = b0; i < b1; i++) {
    int v = bsum[i];
    bsum[i] = base;
    base += v;
  }
  if (t == 255) bsum[NB] = s[255];
}

__global__ __launch_bounds__(256) void scan3_kernel(
    int* __restrict__ row_off, int* __restrict__ cursor,
    const int* __restrict__ bsum, int M, int NB) {
  int i = blockIdx.x * 256 + threadIdx.x;
  if (i < M) {
    int v = row_off[i] + bsum[i >> 8];
    row_off[i] = v;
    cursor[i] = v;
  } else if (i == M) {
    row_off[M] = bsum[NB];
  }
}

// ---------------- bucket edges by (dst,rel); store src | rel<<20 ----------------

__global__ __launch_bounds__(256) void bucket_kernel(
    const int* __restrict__ src, const int* __restrict__ dstp,
    const int* __restrict__ et, int E, int* __restrict__ cursor,
    int* __restrict__ epack) {
  int i = blockIdx.x * blockDim.x + threadIdx.x;
  if (i < E) {
    int r = et[i];
    int pos = atomicAdd(&cursor[(size_t)dstp[i] * NRELS + r], 1);
    epack[pos] = src[i] | (r << 20);
  }
}

// ---------------- MFMA GEMM: xs[N,NC] = A[N,128] @ Bt[NC,128]^T (bf16 out) --------
// Each block: stage A-tile once, loop over TILES col-tiles {stage B, MFMA, store}.

template <int BN, int TILES>
__global__ __launch_bounds__(256) void gemm_xs(
    const unsigned short* __restrict__ A,   // [N][128] bf16
    const unsigned short* __restrict__ Bt,  // [NC][128] bf16
    unsigned short* __restrict__ Cout,      // [N][NC] bf16
    int N, int NC) {
  constexpr int FM = 2;
  constexpr int FN = BN / 32;  // 4 (BN=128) or 2 (BN=64)

  __shared__ unsigned short As[64 * 128];   // 16 KB, 256B rows
  __shared__ unsigned short Bs[BN * 128];   // 32/16 KB

  const int tid = threadIdx.x;
  const int lane = tid & 63;
  const int wid = tid >> 6;
  const int wm = wid >> 1, wn = wid & 1;
  const int l15 = lane & 15, lhi = lane >> 4;
  const int bm0 = blockIdx.y * 64;
  const int ng0 = blockIdx.x * BN * TILES;

  // stage A: 64 rows x 256 B (full K) — once
#pragma unroll
  for (int c = 0; c < 4; c++) {
    int o = c * 4096 + tid * 16;
    int row = o >> 8;
    int scol = ((o & 255) ^ ((row & 7) << 4)) >> 1;
    int gr = bm0 + row;
    gr = gr < N ? gr : N - 1;
    gload_lds16(A + (size_t)gr * 128 + scol, (char*)As + o);
  }

  for (int t = 0; t < TILES; t++) {
    const int n0 = ng0 + t * BN;
    if (t) __syncthreads();  // prev tile's Bs reads complete before restage
    // stage B: BN rows x 256 B
#pragma unroll
    for (int c = 0; c < BN / 16; c++) {
      int o = c * 4096 + tid * 16;
      int n = o >> 8;
      int scol = ((o & 255) ^ ((n & 7) << 4)) >> 1;
      gload_lds16(Bt + (size_t)(n0 + n) * 128 + scol, (char*)Bs + o);
    }
    asm volatile("s_waitcnt vmcnt(0)" ::: "memory");
    __syncthreads();

    f32x4 acc[FM][FN];
#pragma unroll
    for (int i = 0; i < FM; i++)
#pragma unroll
      for (int j = 0; j < FN; j++) acc[i][j] = (f32x4){0.f, 0.f, 0.f, 0.f};

#pragma unroll
    for (int ks = 0; ks < 4; ks++) {
      short8 af[FM], bf[FN];
#pragma unroll
      for (int fm = 0; fm < FM; fm++) {
        int row = wm * 32 + fm * 16 + l15;
        af[fm] = *(const short8*)((const char*)As + row * 256 +
                                  ((ks * 64 + lhi * 16) ^ ((row & 7) << 4)));
      }
#pragma unroll
      for (int fn = 0; fn < FN; fn++) {
        int n = wn * (BN / 2) + fn * 16 + l15;
        bf[fn] = *(const short8*)((const char*)Bs + n * 256 +
                                  ((ks * 64 + lhi * 16) ^ ((n & 7) << 4)));
      }
#pragma unroll
      for (int fm = 0; fm < FM; fm++)
#pragma unroll
        for (int fn = 0; fn < FN; fn++)
          acc[fm][fn] = __builtin_amdgcn_mfma_f32_16x16x32_bf16(
              af[fm], bf[fn], acc[fm][fn], 0, 0, 0);
    }

#pragma unroll
    for (int fm = 0; fm < FM; fm++) {
#pragma unroll
      for (int fn = 0; fn < FN; fn++) {
        int col = n0 + wn * (BN / 2) + fn * 16 + l15;
#pragma unroll
        for (int i = 0; i < 4; i++) {
          int row = bm0 + wm * 32 + fm * 16 + lhi * 4 + i;
          if (row < N) {
            Cout[(size_t)row * NC + col] = f2bf(acc[fm][fn][i]);
          }
        }
      }
    }
  }
}

// ---------------- agg-finish layer 1: flat per-edge loop, 8-deep MLP ----------

__global__ __launch_bounds__(256) void agg_finish1(
    const unsigned short* __restrict__ xs,  // [N][1152] bf16
    const int* __restrict__ row_off,        // [8N+1]
    const int* __restrict__ epack,          // [E] src | rel<<20
    const float* __restrict__ nrm,          // [8N]
    const float* __restrict__ b1,           // [128]
    unsigned short* __restrict__ h,         // [N][128] bf16 out (relu'd)
    int N) {
  int wid = (int)((blockIdx.x * blockDim.x + threadIdx.x) >> 6);
  if (wid >= N) return;
  int lane = threadIdx.x & 63;
  int lo2 = lane * 2;
  unsigned int own = *(const unsigned int*)(xs + (size_t)wid * 1152 + 1024 + lo2);
  float acc0 = bf2f((unsigned short)(own & 0xFFFF)) + b1[lo2];
  float acc1 = bf2f((unsigned short)(own >> 16)) + b1[lo2 + 1];
  int kb = wid * NRELS;
  int b = row_off[kb], e = row_off[kb + NRELS];
  int i = b;
  for (; i + 7 < e; i += 8) {
    unsigned int u[8];
    float nv[8];
#pragma unroll
    for (int q = 0; q < 8; q++) {
      int p = epack[i + q];
      u[q] = *(const unsigned int*)(xs + (size_t)(p & 0xFFFFF) * 1152 + ((p >> 20) << 7) + lo2);
      nv[q] = nrm[kb + (p >> 20)];
    }
#pragma unroll
    for (int q = 0; q < 8; q++) {
      acc0 += bf2f((unsigned short)(u[q] & 0xFFFF)) * nv[q];
      acc1 += bf2f((unsigned short)(u[q] >> 16)) * nv[q];
    }
  }
  for (; i < e; i++) {
    int p = epack[i];
    unsigned int u = *(const unsigned int*)(xs + (size_t)(p & 0xFFFFF) * 1152 + ((p >> 20) << 7) + lo2);
    float nv = nrm[kb + (p >> 20)];
    acc0 += bf2f((unsigned short)(u & 0xFFFF)) * nv;
    acc1 += bf2f((unsigned short)(u >> 16)) * nv;
  }
  unsigned int o = (unsigned int)f2bf(fmaxf(acc0, 0.f)) |
                   ((unsigned int)f2bf(fmaxf(acc1, 0.f)) << 16);
  *(unsigned int*)(h + (size_t)wid * 128 + lo2) = o;
}

// ---------------- agg-finish layer 2: flat per-edge loop (64 cols, fp32 out) ------

__global__ __launch_bounds__(256) void agg_finish2(
    const unsigned short* __restrict__ ys,  // [N][576] bf16
    const int* __restrict__ row_off,        // [8N+1]
    const int* __restrict__ epack,          // [E] src | rel<<20
    const float* __restrict__ nrm,          // [8N]
    const float* __restrict__ b2,           // [64]
    float* __restrict__ outp,               // [N][64] fp32
    int N) {
  int wid = (int)((blockIdx.x * blockDim.x + threadIdx.x) >> 6);
  if (wid >= N) return;
  int col = threadIdx.x & 63;
  float acc = bf2f(ys[(size_t)wid * 576 + 512 + col]) + b2[col];
  int kb = wid * NRELS;
  int b = row_off[kb], e = row_off[kb + NRELS];
  int i = b;
  for (; i + 7 < e; i += 8) {
    float v[8], nv[8];
#pragma unroll
    for (int q = 0; q < 8; q++) {
      int p = epack[i + q];
      v[q] = bf2f(ys[(size_t)(p & 0xFFFFF) * 576 + ((p >> 20) << 6) + col]);
      nv[q] = nrm[kb + (p >> 20)];
    }
#pragma unroll
    for (int q = 0; q < 8; q++) acc += v[q] * nv[q];
  }
  for (; i < e; i++) {
    int p = epack[i];
    acc += bf2f(ys[(size_t)(p & 0xFFFFF) * 576 + ((p >> 20) << 6) + col]) * nrm[kb + (p >> 20)];
  }
  outp[(size_t)wid * 64 + col] = acc;
}

// ---------------- launch ----------------

extern "C" void kernel_launch(void* const* d_in, const int* in_sizes, int n_in,
                              void* d_out, int out_size, void* d_ws, size_t ws_size,
                              hipStream_t stream) {
  const float* x     = (const float*)d_in[0];
  const int*   eidx  = (const int*)d_in[1];
  const int*   et    = (const int*)d_in[2];
  const float* W1    = (const float*)d_in[3];
  const float* root1 = (const float*)d_in[4];
  const float* b1    = (const float*)d_in[5];
  const float* W2    = (const float*)d_in[6];
  const float* root2 = (const float*)d_in[7];
  const float* b2    = (const float*)d_in[8];
  float* out = (float*)d_out;

  const int IN = 128;
  const int N = in_sizes[0] / IN;
  const int E = in_sizes[2];
  const int* src = eidx;
  const int* dst = eidx + E;
  const int M = N * NRELS;            // (dst,rel) key space
  const int NB = (M + 255) / 256;

  auto align = [](size_t v) { return (v + 255) & ~(size_t)255; };
  char* base = (char*)d_ws;
  size_t o = 0;
  int* hist = (int*)(base + o);
  o = align((size_t)M * 4);
  int* row_off = (int*)(base + o);
  o = align(o + (size_t)(M + 1) * 4);
  int* cursor = (int*)(base + o);
  o = align(o + (size_t)M * 4);
  int* bsum = (int*)(base + o);
  o = align(o + (size_t)(NB + 1) * 4);
  float* nrm = (float*)(base + o);
  o = align(o + (size_t)M * 4);
  int* epack = (int*)(base + o);
  o = align(o + (size_t)E * 4);
  unsigned short* xb = (unsigned short*)(base + o);       // [N][128] bf16
  o = align(o + (size_t)N * 128 * 2);
  unsigned short* hb = (unsigned short*)(base + o);       // [N][128] bf16 (relu'd h)
  o = align(o + (size_t)N * 128 * 2);
  unsigned short* Bt1 = (unsigned short*)(base + o);      // [1152][128]
  o = align(o + (size_t)1152 * 128 * 2);
  unsigned short* Bt2 = (unsigned short*)(base + o);      // [576][128]
  o = align(o + (size_t)576 * 128 * 2);
  unsigned short* xs = (unsigned short*)(base + o);       // [N][1152] bf16 (reused as ys)

  const int tb = 256;
  const int n4 = N * IN / 4;
  const int prep_total = n4 + 1152 * 128 + 576 * 128 + E;

  zero_kernel<<<(M + tb - 1) / tb, tb, 0, stream>>>(hist, M);
  prep_kernel<<<(prep_total + tb - 1) / tb, tb, 0, stream>>>(
      x, xb, n4, W1, root1, W2, root2, Bt1, Bt2, dst, et, E, hist);
  scan1_kernel<<<NB, 256, 0, stream>>>(hist, M, row_off, bsum, nrm);
  scan2_kernel<<<1, 256, 0, stream>>>(bsum, NB);
  scan3_kernel<<<(M + 256) / 256, 256, 0, stream>>>(row_off, cursor, bsum, M, NB);
  bucket_kernel<<<(E + tb - 1) / tb, tb, 0, stream>>>(src, dst, et, E, cursor, epack);

  const int agrid = (N + 3) / 4;
  const int gblocks = (N + 63) / 64;

  // layer 1: xs = xb @ Bt1^T ; h = relu(agg(xs) + root-slice + b1)
  {
    dim3 g(3, gblocks);  // 3 col-groups x 3 tiles of 128 = 1152
    gemm_xs<128, 3><<<g, 256, 0, stream>>>(xb, Bt1, xs, N, 1152);
  }
  agg_finish1<<<agrid, 256, 0, stream>>>(xs, row_off, epack, nrm, b1, hb, N);

  // layer 2: ys = hb @ Bt2^T ; out = agg(ys) + root-slice + b2
  {
    dim3 g(3, gblocks);  // 3 col-groups x 3 tiles of 64 = 576
    gemm_xs<64, 3><<<g, 256, 0, stream>>>(hb, Bt2, xs, N, 576);
  }
  agg_finish2<<<agrid, 256, 0, stream>>>(xs, row_off, epack, nrm, b2, out, N);
}